// Round 7
// baseline (499.409 us; speedup 1.0000x reference)
//
#include <hip/hip_runtime.h>
#include <hip/hip_bf16.h>

typedef __bf16 bf16;
typedef __attribute__((ext_vector_type(8))) __bf16 bf16x8;
typedef __attribute__((ext_vector_type(4))) __bf16 bf16x4;
typedef __attribute__((ext_vector_type(4))) float f32x4;

typedef const __attribute__((address_space(1))) void* gptr_t;
typedef __attribute__((address_space(3))) void* sptr_t;

__device__ __forceinline__ void gload16(const void* g, void* l) {
  __builtin_amdgcn_global_load_lds((gptr_t)g, (sptr_t)l, 16, 0, 0);
}

#define MFMA_BF16(a, b, c) __builtin_amdgcn_mfma_f32_16x16x32_bf16((a), (b), (c), 0, 0, 0)

// raw barrier (no vmcnt(0) drain)
#define BAR() do { asm volatile("" ::: "memory"); __builtin_amdgcn_s_barrier(); asm volatile("" ::: "memory"); } while (0)

// st-swizzle: XOR the 16B-slot index (bits 6:4) with the low 3 row bits
// (bits 9:7 of the byte offset, rows are 128B). Involution; bits>=7 unchanged.
__device__ __forceinline__ int swzb(int l) { return l ^ (((l >> 7) & 7) << 4); }

namespace {
constexpr int kB = 2, kS = 2048, kE = 2048, kN = 16, kH = 128;
constexpr float kScale = 0.08838834764831845f;  // 1/sqrt(128)
constexpr float kLog2e = 1.4426950408889634f;
}

// ---------------- f32 -> bf16 convert (both inputs, one launch) ----------------
__global__ void k_cvt2(const float* __restrict__ a, const float* __restrict__ b,
                       bf16* __restrict__ oa, bf16* __restrict__ ob) {
  int bid = blockIdx.x;
  const float* in = (bid < 8192) ? a : b;
  bf16* out = (bid < 8192) ? oa : ob;
  int i = (bid & 8191) * 256 + threadIdx.x;
  float4 v = reinterpret_cast<const float4*>(in)[i];
  bf16x4 o = { (bf16)v.x, (bf16)v.y, (bf16)v.z, (bf16)v.w };
  reinterpret_cast<bf16x4*>(out)[i] = o;
}

// ------------- transpose-convert all 4 weights: in[2048][2048] f32 -> out[c][r] bf16 -------------
__global__ void k_tconv4(const float* __restrict__ WQ, const float* __restrict__ WK,
                         const float* __restrict__ WV, const float* __restrict__ WO,
                         bf16* __restrict__ OQ, bf16* __restrict__ OK2,
                         bf16* __restrict__ OV, bf16* __restrict__ OO) {
  __shared__ float tile[64][68];
  int bid = blockIdx.x;
  int sel = bid >> 10;
  const float* in = (sel == 0) ? WQ : (sel == 1) ? WK : (sel == 2) ? WV : WO;
  bf16* out = (sel == 0) ? OQ : (sel == 1) ? OK2 : (sel == 2) ? OV : OO;
  int lb = bid & 1023;
  int bx = lb & 31, by = lb >> 5;
  int r0 = by * 64, c0 = bx * 64;
  int t = threadIdx.x;
  int rr = t >> 4, c4 = (t & 15) * 4;
#pragma unroll
  for (int k = 0; k < 4; ++k) {
    int r = rr + k * 16;
    float4 v = *reinterpret_cast<const float4*>(&in[(size_t)(r0 + r) * 2048 + c0 + c4]);
    tile[r][c4] = v.x; tile[r][c4 + 1] = v.y; tile[r][c4 + 2] = v.z; tile[r][c4 + 3] = v.w;
  }
  __syncthreads();
  int cc0 = t >> 3, r8 = (t & 7) * 8;
#pragma unroll
  for (int k = 0; k < 2; ++k) {
    int cc = cc0 + k * 32;
    bf16x8 o;
#pragma unroll
    for (int j = 0; j < 8; ++j) o[j] = (bf16)tile[r8 + j][cc];
    *reinterpret_cast<bf16x8*>(&out[(size_t)(c0 + cc) * 2048 + r0 + r8]) = o;
  }
}

// ------------- V transpose: V[bn][S][H] -> Vt[bn][H][S] (bf16, vectorized) -------------
__global__ void k_vtrans(const bf16* __restrict__ V, bf16* __restrict__ Vt) {
  __shared__ bf16 tile[64][72];
  int bid = blockIdx.x;
  int bn = bid >> 6;
  int s0 = ((bid >> 1) & 31) * 64;
  int h0 = (bid & 1) * 64;
  size_t base = (size_t)bn * kS * kH;
  int t = threadIdx.x;
  int r = t >> 3, c8 = (t & 7) * 8;
#pragma unroll
  for (int k = 0; k < 2; ++k) {
    int rr = r + k * 32;
    *reinterpret_cast<bf16x8*>(&tile[rr][c8]) =
        *reinterpret_cast<const bf16x8*>(&V[base + (size_t)(s0 + rr) * kH + h0 + c8]);
  }
  __syncthreads();
  int hh0 = t >> 3, s8 = (t & 7) * 8;
#pragma unroll
  for (int k = 0; k < 2; ++k) {
    int hh = hh0 + k * 32;
    bf16x8 o;
#pragma unroll
    for (int j = 0; j < 8; ++j) o[j] = tile[s8 + j][hh];
    *reinterpret_cast<bf16x8*>(&Vt[base + (size_t)(h0 + hh) * kS + s0 + s8]) = o;
  }
}

// ------------- trig table: ctab/stab[2048][64] -------------
__global__ void k_trig(float* __restrict__ ctab, float* __restrict__ stab) {
  int tid = blockIdx.x * 256 + threadIdx.x;   // 131072
  int s = tid >> 6, i = tid & 63;
  float inv = exp2f(-(float)i * 0.20762050593046457f);  // 10000^(-i/64)
  float ang = (float)s * inv;
  float sn, cs;
  sincosf(ang, &sn, &cs);
  ctab[tid] = cs;
  stab[tid] = sn;
}

// ------------- RoPE in-place on Q and K, [B,N,S,H], table-driven, vectorized -------------
__global__ void k_rope(bf16* __restrict__ Qd, bf16* __restrict__ Kd,
                       const float* __restrict__ ctab, const float* __restrict__ stab) {
  int tid = blockIdx.x * 256 + threadIdx.x;   // 32*2048*8 total
  int i8 = (tid & 7) * 8;
  int s = (tid >> 3) & (kS - 1);
  int bn = tid >> 14;
  size_t base = ((size_t)bn * kS + s) * kH;
  float4 c0 = *reinterpret_cast<const float4*>(&ctab[(s << 6) + i8]);
  float4 c1 = *reinterpret_cast<const float4*>(&ctab[(s << 6) + i8 + 4]);
  float4 s0 = *reinterpret_cast<const float4*>(&stab[(s << 6) + i8]);
  float4 s1 = *reinterpret_cast<const float4*>(&stab[(s << 6) + i8 + 4]);
  float cs[8] = {c0.x, c0.y, c0.z, c0.w, c1.x, c1.y, c1.z, c1.w};
  float sn[8] = {s0.x, s0.y, s0.z, s0.w, s1.x, s1.y, s1.z, s1.w};
  bf16x8 qlo = *reinterpret_cast<const bf16x8*>(&Qd[base + i8]);
  bf16x8 qhi = *reinterpret_cast<const bf16x8*>(&Qd[base + 64 + i8]);
  bf16x8 klo = *reinterpret_cast<const bf16x8*>(&Kd[base + i8]);
  bf16x8 khi = *reinterpret_cast<const bf16x8*>(&Kd[base + 64 + i8]);
  bf16x8 qlo2, qhi2, klo2, khi2;
#pragma unroll
  for (int j = 0; j < 8; ++j) {
    float q1 = (float)qlo[j], q2 = (float)qhi[j];
    qlo2[j] = (bf16)(q1 * cs[j] - q2 * sn[j]);
    qhi2[j] = (bf16)(q2 * cs[j] + q1 * sn[j]);
    float k1 = (float)klo[j], k2 = (float)khi[j];
    klo2[j] = (bf16)(k1 * cs[j] - k2 * sn[j]);
    khi2[j] = (bf16)(k2 * cs[j] + k1 * sn[j]);
  }
  *reinterpret_cast<bf16x8*>(&Qd[base + i8]) = qlo2;
  *reinterpret_cast<bf16x8*>(&Qd[base + 64 + i8]) = qhi2;
  *reinterpret_cast<bf16x8*>(&Kd[base + i8]) = klo2;
  *reinterpret_cast<bf16x8*>(&Kd[base + 64 + i8]) = khi2;
}

// ======== 8-phase GEMM, 128x256 tiles, BK=64, 8 waves (2M x 4N) ========
// MODE 0: QKV fused (Ncols=6144, 768 blocks = 3 full rounds), scatter bf16.
// MODE 1: out-proj (Ncols=2048, 256 blocks), write f32 [M][2048].
// LDS: A double-buf 2x16KB @0, B triple-buf 3x32KB @32768 = 128KB.

__device__ __forceinline__ void stage_half(const bf16* __restrict__ src, size_t row0,
                                           int k0, char* slot, int t) {
#pragma unroll
  for (int i = 0; i < 2; ++i) {
    int idx = i * 512 + t;               // 0..1023
    int d = idx * 16;                    // physical LDS byte this thread fills
    int lb = d ^ (((d >> 7) & 7) << 4);  // logical byte (involution)
    int r = lb >> 7;                     // logical row 0..127
    int kc = (lb & 127) >> 1;            // logical k-col (bf16), 16B-aligned
    gload16(src + (row0 + r) * 2048 + k0 + kc,
            slot + i * 8192 + (t >> 6) * 1024);
  }
}

#define AS1(b)    ((char*)LDS + (b) * 16384)
#define BS1(q, h) ((char*)LDS + 32768 + (q) * 32768 + (h) * 16384)

template <int MODE>
__global__ __launch_bounds__(512, 2) void k_gemm8(const bf16* __restrict__ Aq,
                                                  const bf16* __restrict__ Akv,
                                                  const bf16* __restrict__ Bt,
                                                  void* __restrict__ Cout) {
  constexpr int NTN = (MODE == 0) ? 24 : 8;     // N-tiles (256 wide)
  constexpr int NTM = 32;                       // M-tiles (128 tall)
  constexpr int NT = 32;                        // K-tiles (2048/64)
  __shared__ __align__(16) char LDS[131072];
  int bid = blockIdx.x;
  constexpr int nblk = NTM * NTN;
  int swz = (bid & 7) * (nblk >> 3) + (bid >> 3);  // XCD-aware (nblk%8==0)
  int mt = swz / NTN, nt = swz - mt * NTN;
  size_t m0 = (size_t)mt * 128;
  int n0 = nt * 256;
  const bf16* A = (MODE == 0 && nt >= 8) ? Akv : Aq;  // K,V read x_kv
  int t = threadIdx.x, wid = t >> 6, lane = t & 63;
  int l16 = lane & 15, lq = lane >> 4;
  int wr = wid >> 2, wc = wid & 3;          // 2M x 4N wave grid
  int bhalf = wc >> 1;                      // B half this wave reads
  int brow0 = ((wc & 1) << 6) + l16;        // row-in-half base for B frags

  f32x4 acc[4][4] = {};
  bf16x8 af[4], bfr[4];

  stage_half(Bt, (size_t)n0,       0, BS1(0, 0), t);
  stage_half(Bt, (size_t)n0 + 128, 0, BS1(0, 1), t);
  stage_half(A,  m0,               0, AS1(0), t);
  stage_half(Bt, (size_t)n0,      64, BS1(1, 0), t);
  stage_half(Bt, (size_t)n0 + 128, 64, BS1(1, 1), t);
  asm volatile("s_waitcnt vmcnt(4)" ::: "memory");
  BAR();

  int bql = 0;  // kt % 3
  for (int kt = 0; kt < NT; ++kt) {
    char* Ab = AS1(kt & 1);
    char* Anb = AS1((kt & 1) ^ 1);
    char* Bb = BS1(bql, bhalf);
    int bq2 = bql + 2; if (bq2 >= 3) bq2 -= 3;
    // ---------- P1: kf=0, nf{0,1}; stage A(kt+1) ----------
#pragma unroll
    for (int j = 0; j < 4; ++j) {
      int l = (((wr * 4 + j) * 16 + l16) << 7) + (lq << 4);
      af[j] = *(const bf16x8*)(Ab + swzb(l));
    }
#pragma unroll
    for (int nf = 0; nf < 2; ++nf) {
      int l = ((brow0 + nf * 16) << 7) + (lq << 4);
      bfr[nf] = *(const bf16x8*)(Bb + swzb(l));
    }
    if (kt + 1 < NT) stage_half(A, m0, (kt + 1) * 64, Anb, t);
    BAR();
    __builtin_amdgcn_s_setprio(1);
#pragma unroll
    for (int j = 0; j < 4; ++j)
#pragma unroll
      for (int nf = 0; nf < 2; ++nf)
        acc[j][nf] = MFMA_BF16(af[j], bfr[nf], acc[j][nf]);
    __builtin_amdgcn_s_setprio(0);
    BAR();
    // ---------- P2: kf=0, nf{2,3}; stage B(kt+2) ----------
#pragma unroll
    for (int nf = 0; nf < 2; ++nf) {
      int l = ((brow0 + (nf + 2) * 16) << 7) + (lq << 4);
      bfr[2 + nf] = *(const bf16x8*)(Bb + swzb(l));
    }
    if (kt + 2 < NT) {
      stage_half(Bt, (size_t)n0,       (kt + 2) * 64, BS1(bq2, 0), t);
      stage_half(Bt, (size_t)n0 + 128, (kt + 2) * 64, BS1(bq2, 1), t);
    }
    BAR();
    __builtin_amdgcn_s_setprio(1);
#pragma unroll
    for (int j = 0; j < 4; ++j)
#pragma unroll
      for (int nf = 0; nf < 2; ++nf)
        acc[j][2 + nf] = MFMA_BF16(af[j], bfr[2 + nf], acc[j][2 + nf]);
    __builtin_amdgcn_s_setprio(0);
    BAR();
    // ---------- P3: kf=1, nf{0,1} ----------
#pragma unroll
    for (int j = 0; j < 4; ++j) {
      int l = (((wr * 4 + j) * 16 + l16) << 7) + 64 + (lq << 4);
      af[j] = *(const bf16x8*)(Ab + swzb(l));
    }
#pragma unroll
    for (int nf = 0; nf < 2; ++nf) {
      int l = ((brow0 + nf * 16) << 7) + 64 + (lq << 4);
      bfr[nf] = *(const bf16x8*)(Bb + swzb(l));
    }
    BAR();
    __builtin_amdgcn_s_setprio(1);
#pragma unroll
    for (int j = 0; j < 4; ++j)
#pragma unroll
      for (int nf = 0; nf < 2; ++nf)
        acc[j][nf] = MFMA_BF16(af[j], bfr[nf], acc[j][nf]);
    __builtin_amdgcn_s_setprio(0);
    BAR();
    // ---------- P4: kf=1, nf{2,3}; counted vmcnt ----------
#pragma unroll
    for (int nf = 0; nf < 2; ++nf) {
      int l = ((brow0 + (nf + 2) * 16) << 7) + 64 + (lq << 4);
      bfr[2 + nf] = *(const bf16x8*)(Bb + swzb(l));
    }
    BAR();
    __builtin_amdgcn_s_setprio(1);
#pragma unroll
    for (int j = 0; j < 4; ++j)
#pragma unroll
      for (int nf = 0; nf < 2; ++nf)
        acc[j][2 + nf] = MFMA_BF16(af[j], bfr[2 + nf], acc[j][2 + nf]);
    __builtin_amdgcn_s_setprio(0);
    if (kt < NT - 2)       asm volatile("s_waitcnt vmcnt(4)" ::: "memory");
    else if (kt == NT - 2) asm volatile("s_waitcnt vmcnt(0)" ::: "memory");
    BAR();
    bql += 1; if (bql >= 3) bql -= 3;
  }

  // ---- epilogue: C write ----
#pragma unroll
  for (int mf = 0; mf < 4; ++mf) {
    int rowb = (int)m0 + wr * 64 + mf * 16 + lq * 4;
#pragma unroll
    for (int nf = 0; nf < 4; ++nf) {
      int col = n0 + wc * 64 + nf * 16 + l16;
#pragma unroll
      for (int r = 0; r < 4; ++r) {
        float v = acc[mf][nf][r];
        int mrow = rowb + r;
        if (MODE == 0) {
          int grp = col >> 11, cw = col & 2047;
          int b = mrow >> 11, s = mrow & 2047, n = cw >> 7, h = cw & 127;
          ((bf16*)Cout)[(size_t)grp * 8388608 +
                        (((size_t)(b * 16 + n) * 2048 + s) << 7) + h] = (bf16)v;
        } else {
          ((float*)Cout)[((size_t)mrow << 11) + col] = v;
        }
      }
    }
  }
}

// ------------- Flash attention (causal): Q,K [B,N,S,H], Vt [B,N,H,S] -> AO [B,S,N,H] -------------
// Double-buffered K/V staging (T3/T4 minimum 2-phase): STAGE(next) issued BEFORE
// compute, one vmcnt(0)+s_barrier per tile. 80KB LDS -> 2 blocks/CU, whole grid
// co-resident; complementary qt pairing keeps per-CU work uniform.
__global__ __launch_bounds__(512, 2) void k_attn(const bf16* __restrict__ Q,
                                                 const bf16* __restrict__ Kg,
                                                 const bf16* __restrict__ Vt,
                                                 bf16* __restrict__ AO) {
  __shared__ __align__(16) bf16 Ks[2][64 * 128];   // [s'][h], chunk-swizzled
  __shared__ __align__(16) bf16 Vs[2][128 * 64];   // [h][s'], chunk-swizzled
  __shared__ __align__(16) bf16 Ps[8 * 16 * 64];   // per-wave P, XOR-swizzled
  int bid = blockIdx.x;
  int half = bid >> 8;
  int bn = (half << 4) | ((bid >> 4) & 15);
  int qt = (bid & 15) ^ (half ? 15 : 0);
  int q0 = qt * 128;
  int t = threadIdx.x, wid = t >> 6, lane = t & 63;
  int l16 = lane & 15, lq = lane >> 4;
  size_t bnSH = (size_t)bn * kS * kH;

  int qrow_a = q0 + wid * 16 + l16;
  bf16x8 qf[4];
#pragma unroll
  for (int ks = 0; ks < 4; ++ks)
    qf[ks] = *(const bf16x8*)(Q + bnSH + (size_t)qrow_a * kH + ks * 32 + lq * 8);

  f32x4 oacc[8] = {};
  float mrun[4], lrun[4];
#pragma unroll
  for (int r = 0; r < 4; ++r) { mrun[r] = -1e30f; lrun[r] = 0.f; }

  auto STAGE = [&](int b, int kt) {
    int kv0 = kt * 64;
#pragma unroll
    for (int i = 0; i < 2; ++i) {
      int idx = i * 512 + t;
      {
        int row = idx >> 4, ch = idx & 15;
        int gch = ch ^ (row & 7);
        gload16(Kg + bnSH + (size_t)(kv0 + row) * kH + gch * 8,
                (char*)&Ks[b][0] + i * 8192 + wid * 1024);
      }
      {
        int row = idx >> 3, ch = idx & 7;
        int gch = ch ^ (row & 7);
        gload16(Vt + bnSH + (size_t)row * kS + kv0 + gch * 8,
                (char*)&Vs[b][0] + i * 8192 + wid * 1024);
      }
    }
  };

  int ntiles = (q0 + 128) >> 6;
  STAGE(0, 0);
  asm volatile("s_waitcnt vmcnt(0)" ::: "memory");
  BAR();

  int buf = 0;
  for (int kt = 0; kt < ntiles; ++kt) {
    int kv0 = kt * 64;
    if (kt + 1 < ntiles) STAGE(buf ^ 1, kt + 1);   // prefetch next tile

    f32x4 sacc[4] = {};
    const char* Kb = (const char*)&Ks[buf][0];
    const char* Vb = (const char*)&Vs[buf][0];
#pragma unroll
    for (int ks = 0; ks < 4; ++ks) {
#pragma unroll
      for (int ni = 0; ni < 4; ++ni) {
        int sp = ni * 16 + l16;
        int hb = (ks * 32 + lq * 8) * 2;
        bf16x8 kb = *(const bf16x8*)(Kb + sp * 256 + (hb ^ ((sp & 7) << 4)));
        __builtin_amdgcn_s_setprio(1);
        sacc[ni] = MFMA_BF16(qf[ks], kb, sacc[ni]);
        __builtin_amdgcn_s_setprio(0);
      }
    }

    bool need_mask = (kv0 + 63) > (q0 + wid * 16);
#pragma unroll
    for (int ni = 0; ni < 4; ++ni) {
      f32x4 v = sacc[ni] * kScale;
      if (need_mask) {
#pragma unroll
        for (int r = 0; r < 4; ++r) {
          int qrow = q0 + wid * 16 + lq * 4 + r;
          int col = kv0 + ni * 16 + l16;
          if (col > qrow) v[r] = -1e30f;
        }
      }
      sacc[ni] = v;
    }

#pragma unroll
    for (int r = 0; r < 4; ++r) {
      float pm = fmaxf(fmaxf(sacc[0][r], sacc[1][r]),
                       fmaxf(sacc[2][r], sacc[3][r]));
      pm = fmaxf(pm, __shfl_xor(pm, 1));
      pm = fmaxf(pm, __shfl_xor(pm, 2));
      pm = fmaxf(pm, __shfl_xor(pm, 4));
      pm = fmaxf(pm, __shfl_xor(pm, 8));
      float mold = mrun[r];
      float mnew = fmaxf(mold, pm);
      float alpha = exp2f((mold - mnew) * kLog2e);
      mrun[r] = mnew;
      float rs = 0.f;
#pragma unroll
      for (int ni = 0; ni < 4; ++ni) {
        float p = exp2f((sacc[ni][r] - mnew) * kLog2e);
        sacc[ni][r] = p;
        rs += p;
      }
      rs += __shfl_xor(rs, 1);
      rs += __shfl_xor(rs, 2);
      rs += __shfl_xor(rs, 4);
      rs += __shfl_xor(rs, 8);
      lrun[r] = lrun[r] * alpha + rs;
#pragma unroll
      for (int nj = 0; nj < 8; ++nj) oacc[nj][r] *= alpha;
    }

    // write P (bf16) to per-wave LDS, XOR-swizzled rows (read by same wave only)
#pragma unroll
    for (int ni = 0; ni < 4; ++ni)
#pragma unroll
      for (int r = 0; r < 4; ++r) {
        int row = lq * 4 + r;
        int byte = (row << 7) + ((ni * 16 + l16) << 1);
        *(bf16*)((char*)Ps + wid * 2048 + (byte ^ ((row & 7) << 4))) = (bf16)sacc[ni][r];
      }

#pragma unroll
    for (int ks = 0; ks < 2; ++ks) {
      int pb = (l16 << 7) + ((ks * 64 + lq * 16) ^ ((l16 & 7) << 4));
      bf16x8 pa = *(const bf16x8*)((const char*)Ps + wid * 2048 + pb);
#pragma unroll
      for (int nj = 0; nj < 8; ++nj) {
        int h = nj * 16 + l16;
        int sb = (ks * 64 + lq * 16) ^ ((h & 7) << 4);
        bf16x8 vb = *(const bf16x8*)(Vb + h * 128 + sb);
        __builtin_amdgcn_s_setprio(1);
        oacc[nj] = MFMA_BF16(pa, vb, oacc[nj]);
        __builtin_amdgcn_s_setprio(0);
      }
    }

    // next-tile loads must have landed (they had the whole compute phase);
    // barrier releases buf^1 for reading and buf for overwriting.
    asm volatile("s_waitcnt vmcnt(0)" ::: "memory");
    BAR();
    buf ^= 1;
  }

  int b = bn >> 4, n = bn & 15;
#pragma unroll
  for (int r = 0; r < 4; ++r) {
    float inv = 1.0f / lrun[r];
    int qrow = q0 + wid * 16 + lq * 4 + r;
#pragma unroll
    for (int nj = 0; nj < 8; ++nj) {
      float v = oacc[nj][r] * inv;
      AO[(((size_t)b * kS + qrow) * kN + n) * kH + nj * 16 + l16] = (bf16)v;
    }
  }
}

extern "C" void kernel_launch(void* const* d_in, const int* in_sizes, int n_in,
                              void* d_out, int out_size, void* d_ws, size_t ws_size,
                              hipStream_t stream) {
  (void)in_sizes; (void)n_in; (void)out_size; (void)ws_size;
  const float* x_q  = (const float*)d_in[0];
  const float* x_kv = (const float*)d_in[1];
  const float* WQ   = (const float*)d_in[2];
  const float* WK   = (const float*)d_in[3];
  const float* WV   = (const float*)d_in[4];
  const float* WO   = (const float*)d_in[5];
  float* out = (float*)d_out;
  char* w = (char*)d_ws;
  const size_t MB = 1ull << 20;
  bf16* xq  = (bf16*)(w + 0 * MB);    // 16MB; reused: trig tables, then AO
  bf16* xkv = (bf16*)(w + 16 * MB);   // 16MB; reused as Vt
  bf16* WqT = (bf16*)(w + 32 * MB);   // WqT/WkT/WvT contiguous = fused [6144][2048]
  bf16* WkT = (bf16*)(w + 40 * MB);
  bf16* WvT = (bf16*)(w + 48 * MB);
  bf16* WoT = (bf16*)(w + 56 * MB);
  bf16* Qb  = (bf16*)(w + 64 * MB);   // [B,N,S,H]; Kb=+16MB, Vb=+32MB (grp indexed)
  bf16* Kb  = (bf16*)(w + 80 * MB);
  bf16* Vb  = (bf16*)(w + 96 * MB);
  float* ctab = (float*)(w + 0 * MB); // lives in dead xq region (after QKV GEMM)
  float* stab = (float*)(w + 1 * MB);
  bf16* AO  = xq;                     // [B,S,N,H] — written by attn (tables dead by then)
  bf16* Vtb = xkv;                    // [B,N,H,S]

  k_cvt2<<<16384, 256, 0, stream>>>(x_q, x_kv, xq, xkv);
  k_tconv4<<<4096, 256, 0, stream>>>(WQ, WK, WV, WO, WqT, WkT, WvT, WoT);
  k_gemm8<0><<<768, 512, 0, stream>>>(xq, xkv, WqT, Qb);   // fused QKV
  k_trig<<<512, 256, 0, stream>>>(ctab, stab);             // xq dead -> tables
  k_rope<<<2048, 256, 0, stream>>>(Qb, Kb, ctab, stab);
  k_vtrans<<<2048, 256, 0, stream>>>(Vb, Vtb);
  k_attn<<<512, 512, 0, stream>>>(Qb, Kb, Vtb, AO);        // AO overwrites tables (dead)
  k_gemm8<1><<<256, 512, 0, stream>>>(AO, AO, WoT, out);   // output proj
}

// Round 8
// 438.722 us; speedup vs baseline: 1.1383x; 1.1383x over previous
//
#include <hip/hip_runtime.h>
#include <hip/hip_bf16.h>

typedef __bf16 bf16;
typedef __attribute__((ext_vector_type(8))) __bf16 bf16x8;
typedef __attribute__((ext_vector_type(4))) __bf16 bf16x4;
typedef __attribute__((ext_vector_type(4))) float f32x4;

typedef const __attribute__((address_space(1))) void* gptr_t;
typedef __attribute__((address_space(3))) void* sptr_t;

__device__ __forceinline__ void gload16(const void* g, void* l) {
  __builtin_amdgcn_global_load_lds((gptr_t)g, (sptr_t)l, 16, 0, 0);
}

#define MFMA_BF16(a, b, c) __builtin_amdgcn_mfma_f32_16x16x32_bf16((a), (b), (c), 0, 0, 0)

// raw barrier (no vmcnt(0) drain)
#define BAR() do { asm volatile("" ::: "memory"); __builtin_amdgcn_s_barrier(); asm volatile("" ::: "memory"); } while (0)

// st-swizzle: XOR the 16B-slot index (bits 6:4) with the low 3 row bits
// (bits 9:7 of the byte offset, rows are 128B). Involution; bits>=7 unchanged.
__device__ __forceinline__ int swzb(int l) { return l ^ (((l >> 7) & 7) << 4); }

namespace {
constexpr int kB = 2, kS = 2048, kE = 2048, kN = 16, kH = 128;
constexpr float kScale = 0.08838834764831845f;  // 1/sqrt(128)
constexpr float kLog2e = 1.4426950408889634f;
}

// ---------------- f32 -> bf16 convert (both inputs, one launch) ----------------
__global__ void k_cvt2(const float* __restrict__ a, const float* __restrict__ b,
                       bf16* __restrict__ oa, bf16* __restrict__ ob) {
  int bid = blockIdx.x;
  const float* in = (bid < 8192) ? a : b;
  bf16* out = (bid < 8192) ? oa : ob;
  int i = (bid & 8191) * 256 + threadIdx.x;
  float4 v = reinterpret_cast<const float4*>(in)[i];
  bf16x4 o = { (bf16)v.x, (bf16)v.y, (bf16)v.z, (bf16)v.w };
  reinterpret_cast<bf16x4*>(out)[i] = o;
}

// ------------- transpose-convert all 4 weights: in[2048][2048] f32 -> out[c][r] bf16 -------------
__global__ void k_tconv4(const float* __restrict__ WQ, const float* __restrict__ WK,
                         const float* __restrict__ WV, const float* __restrict__ WO,
                         bf16* __restrict__ OQ, bf16* __restrict__ OK2,
                         bf16* __restrict__ OV, bf16* __restrict__ OO) {
  __shared__ float tile[64][68];
  int bid = blockIdx.x;
  int sel = bid >> 10;
  const float* in = (sel == 0) ? WQ : (sel == 1) ? WK : (sel == 2) ? WV : WO;
  bf16* out = (sel == 0) ? OQ : (sel == 1) ? OK2 : (sel == 2) ? OV : OO;
  int lb = bid & 1023;
  int bx = lb & 31, by = lb >> 5;
  int r0 = by * 64, c0 = bx * 64;
  int t = threadIdx.x;
  int rr = t >> 4, c4 = (t & 15) * 4;
#pragma unroll
  for (int k = 0; k < 4; ++k) {
    int r = rr + k * 16;
    float4 v = *reinterpret_cast<const float4*>(&in[(size_t)(r0 + r) * 2048 + c0 + c4]);
    tile[r][c4] = v.x; tile[r][c4 + 1] = v.y; tile[r][c4 + 2] = v.z; tile[r][c4 + 3] = v.w;
  }
  __syncthreads();
  int cc0 = t >> 3, r8 = (t & 7) * 8;
#pragma unroll
  for (int k = 0; k < 2; ++k) {
    int cc = cc0 + k * 32;
    bf16x8 o;
#pragma unroll
    for (int j = 0; j < 8; ++j) o[j] = (bf16)tile[r8 + j][cc];
    *reinterpret_cast<bf16x8*>(&out[(size_t)(c0 + cc) * 2048 + r0 + r8]) = o;
  }
}

// ------------- V transpose: V[bn][S][H] -> Vt[bn][H][S] (bf16, vectorized) -------------
__global__ void k_vtrans(const bf16* __restrict__ V, bf16* __restrict__ Vt) {
  __shared__ bf16 tile[64][72];
  int bid = blockIdx.x;
  int bn = bid >> 6;
  int s0 = ((bid >> 1) & 31) * 64;
  int h0 = (bid & 1) * 64;
  size_t base = (size_t)bn * kS * kH;
  int t = threadIdx.x;
  int r = t >> 3, c8 = (t & 7) * 8;
#pragma unroll
  for (int k = 0; k < 2; ++k) {
    int rr = r + k * 32;
    *reinterpret_cast<bf16x8*>(&tile[rr][c8]) =
        *reinterpret_cast<const bf16x8*>(&V[base + (size_t)(s0 + rr) * kH + h0 + c8]);
  }
  __syncthreads();
  int hh0 = t >> 3, s8 = (t & 7) * 8;
#pragma unroll
  for (int k = 0; k < 2; ++k) {
    int hh = hh0 + k * 32;
    bf16x8 o;
#pragma unroll
    for (int j = 0; j < 8; ++j) o[j] = tile[s8 + j][hh];
    *reinterpret_cast<bf16x8*>(&Vt[base + (size_t)(h0 + hh) * kS + s0 + s8]) = o;
  }
}

// ------------- trig table: ctab/stab[2048][64] -------------
__global__ void k_trig(float* __restrict__ ctab, float* __restrict__ stab) {
  int tid = blockIdx.x * 256 + threadIdx.x;   // 131072
  int s = tid >> 6, i = tid & 63;
  float inv = exp2f(-(float)i * 0.20762050593046457f);  // 10000^(-i/64)
  float ang = (float)s * inv;
  float sn, cs;
  sincosf(ang, &sn, &cs);
  ctab[tid] = cs;
  stab[tid] = sn;
}

// ------------- RoPE in-place on Q and K, [B,N,S,H], table-driven, vectorized -------------
__global__ void k_rope(bf16* __restrict__ Qd, bf16* __restrict__ Kd,
                       const float* __restrict__ ctab, const float* __restrict__ stab) {
  int tid = blockIdx.x * 256 + threadIdx.x;   // 32*2048*8 total
  int i8 = (tid & 7) * 8;
  int s = (tid >> 3) & (kS - 1);
  int bn = tid >> 14;
  size_t base = ((size_t)bn * kS + s) * kH;
  float4 c0 = *reinterpret_cast<const float4*>(&ctab[(s << 6) + i8]);
  float4 c1 = *reinterpret_cast<const float4*>(&ctab[(s << 6) + i8 + 4]);
  float4 s0 = *reinterpret_cast<const float4*>(&stab[(s << 6) + i8]);
  float4 s1 = *reinterpret_cast<const float4*>(&stab[(s << 6) + i8 + 4]);
  float cs[8] = {c0.x, c0.y, c0.z, c0.w, c1.x, c1.y, c1.z, c1.w};
  float sn[8] = {s0.x, s0.y, s0.z, s0.w, s1.x, s1.y, s1.z, s1.w};
  bf16x8 qlo = *reinterpret_cast<const bf16x8*>(&Qd[base + i8]);
  bf16x8 qhi = *reinterpret_cast<const bf16x8*>(&Qd[base + 64 + i8]);
  bf16x8 klo = *reinterpret_cast<const bf16x8*>(&Kd[base + i8]);
  bf16x8 khi = *reinterpret_cast<const bf16x8*>(&Kd[base + 64 + i8]);
  bf16x8 qlo2, qhi2, klo2, khi2;
#pragma unroll
  for (int j = 0; j < 8; ++j) {
    float q1 = (float)qlo[j], q2 = (float)qhi[j];
    qlo2[j] = (bf16)(q1 * cs[j] - q2 * sn[j]);
    qhi2[j] = (bf16)(q2 * cs[j] + q1 * sn[j]);
    float k1 = (float)klo[j], k2 = (float)khi[j];
    klo2[j] = (bf16)(k1 * cs[j] - k2 * sn[j]);
    khi2[j] = (bf16)(k2 * cs[j] + k1 * sn[j]);
  }
  *reinterpret_cast<bf16x8*>(&Qd[base + i8]) = qlo2;
  *reinterpret_cast<bf16x8*>(&Qd[base + 64 + i8]) = qhi2;
  *reinterpret_cast<bf16x8*>(&Kd[base + i8]) = klo2;
  *reinterpret_cast<bf16x8*>(&Kd[base + 64 + i8]) = khi2;
}

// ======== 8-phase GEMM, 128x256 tiles, BK=64, 8 waves (2M x 4N) ========
// MODE 0: QKV fused (Ncols=6144, 768 blocks = 3 full rounds), scatter bf16.
// MODE 1: out-proj (Ncols=2048, 256 blocks), write f32 [M][2048].
// LDS: A double-buf 2x16KB @0, B triple-buf 3x32KB @32768 = 128KB.

__device__ __forceinline__ void stage_half(const bf16* __restrict__ src, size_t row0,
                                           int k0, char* slot, int t) {
#pragma unroll
  for (int i = 0; i < 2; ++i) {
    int idx = i * 512 + t;               // 0..1023
    int d = idx * 16;                    // physical LDS byte this thread fills
    int lb = d ^ (((d >> 7) & 7) << 4);  // logical byte (involution)
    int r = lb >> 7;                     // logical row 0..127
    int kc = (lb & 127) >> 1;            // logical k-col (bf16), 16B-aligned
    gload16(src + (row0 + r) * 2048 + k0 + kc,
            slot + i * 8192 + (t >> 6) * 1024);
  }
}

#define AS1(b)    ((char*)LDS + (b) * 16384)
#define BS1(q, h) ((char*)LDS + 32768 + (q) * 32768 + (h) * 16384)

template <int MODE>
__global__ __launch_bounds__(512, 2) void k_gemm8(const bf16* __restrict__ Aq,
                                                  const bf16* __restrict__ Akv,
                                                  const bf16* __restrict__ Bt,
                                                  void* __restrict__ Cout) {
  constexpr int NTN = (MODE == 0) ? 24 : 8;     // N-tiles (256 wide)
  constexpr int NTM = 32;                       // M-tiles (128 tall)
  constexpr int NT = 32;                        // K-tiles (2048/64)
  __shared__ __align__(16) char LDS[131072];
  int bid = blockIdx.x;
  constexpr int nblk = NTM * NTN;
  int swz = (bid & 7) * (nblk >> 3) + (bid >> 3);  // XCD-aware (nblk%8==0)
  int mt = swz / NTN, nt = swz - mt * NTN;
  size_t m0 = (size_t)mt * 128;
  int n0 = nt * 256;
  const bf16* A = (MODE == 0 && nt >= 8) ? Akv : Aq;  // K,V read x_kv
  int t = threadIdx.x, wid = t >> 6, lane = t & 63;
  int l16 = lane & 15, lq = lane >> 4;
  int wr = wid >> 2, wc = wid & 3;          // 2M x 4N wave grid
  int bhalf = wc >> 1;                      // B half this wave reads
  int brow0 = ((wc & 1) << 6) + l16;        // row-in-half base for B frags

  f32x4 acc[4][4] = {};
  bf16x8 af[4], bfr[4];

  stage_half(Bt, (size_t)n0,       0, BS1(0, 0), t);
  stage_half(Bt, (size_t)n0 + 128, 0, BS1(0, 1), t);
  stage_half(A,  m0,               0, AS1(0), t);
  stage_half(Bt, (size_t)n0,      64, BS1(1, 0), t);
  stage_half(Bt, (size_t)n0 + 128, 64, BS1(1, 1), t);
  asm volatile("s_waitcnt vmcnt(4)" ::: "memory");
  BAR();

  int bql = 0;  // kt % 3
  for (int kt = 0; kt < NT; ++kt) {
    char* Ab = AS1(kt & 1);
    char* Anb = AS1((kt & 1) ^ 1);
    char* Bb = BS1(bql, bhalf);
    int bq2 = bql + 2; if (bq2 >= 3) bq2 -= 3;
    // ---------- P1: kf=0, nf{0,1}; stage A(kt+1) ----------
#pragma unroll
    for (int j = 0; j < 4; ++j) {
      int l = (((wr * 4 + j) * 16 + l16) << 7) + (lq << 4);
      af[j] = *(const bf16x8*)(Ab + swzb(l));
    }
#pragma unroll
    for (int nf = 0; nf < 2; ++nf) {
      int l = ((brow0 + nf * 16) << 7) + (lq << 4);
      bfr[nf] = *(const bf16x8*)(Bb + swzb(l));
    }
    if (kt + 1 < NT) stage_half(A, m0, (kt + 1) * 64, Anb, t);
    BAR();
    __builtin_amdgcn_s_setprio(1);
#pragma unroll
    for (int j = 0; j < 4; ++j)
#pragma unroll
      for (int nf = 0; nf < 2; ++nf)
        acc[j][nf] = MFMA_BF16(af[j], bfr[nf], acc[j][nf]);
    __builtin_amdgcn_s_setprio(0);
    BAR();
    // ---------- P2: kf=0, nf{2,3}; stage B(kt+2) ----------
#pragma unroll
    for (int nf = 0; nf < 2; ++nf) {
      int l = ((brow0 + (nf + 2) * 16) << 7) + (lq << 4);
      bfr[2 + nf] = *(const bf16x8*)(Bb + swzb(l));
    }
    if (kt + 2 < NT) {
      stage_half(Bt, (size_t)n0,       (kt + 2) * 64, BS1(bq2, 0), t);
      stage_half(Bt, (size_t)n0 + 128, (kt + 2) * 64, BS1(bq2, 1), t);
    }
    BAR();
    __builtin_amdgcn_s_setprio(1);
#pragma unroll
    for (int j = 0; j < 4; ++j)
#pragma unroll
      for (int nf = 0; nf < 2; ++nf)
        acc[j][2 + nf] = MFMA_BF16(af[j], bfr[2 + nf], acc[j][2 + nf]);
    __builtin_amdgcn_s_setprio(0);
    BAR();
    // ---------- P3: kf=1, nf{0,1} ----------
#pragma unroll
    for (int j = 0; j < 4; ++j) {
      int l = (((wr * 4 + j) * 16 + l16) << 7) + 64 + (lq << 4);
      af[j] = *(const bf16x8*)(Ab + swzb(l));
    }
#pragma unroll
    for (int nf = 0; nf < 2; ++nf) {
      int l = ((brow0 + nf * 16) << 7) + 64 + (lq << 4);
      bfr[nf] = *(const bf16x8*)(Bb + swzb(l));
    }
    BAR();
    __builtin_amdgcn_s_setprio(1);
#pragma unroll
    for (int j = 0; j < 4; ++j)
#pragma unroll
      for (int nf = 0; nf < 2; ++nf)
        acc[j][nf] = MFMA_BF16(af[j], bfr[nf], acc[j][nf]);
    __builtin_amdgcn_s_setprio(0);
    BAR();
    // ---------- P4: kf=1, nf{2,3}; counted vmcnt ----------
#pragma unroll
    for (int nf = 0; nf < 2; ++nf) {
      int l = ((brow0 + (nf + 2) * 16) << 7) + 64 + (lq << 4);
      bfr[2 + nf] = *(const bf16x8*)(Bb + swzb(l));
    }
    BAR();
    __builtin_amdgcn_s_setprio(1);
#pragma unroll
    for (int j = 0; j < 4; ++j)
#pragma unroll
      for (int nf = 0; nf < 2; ++nf)
        acc[j][2 + nf] = MFMA_BF16(af[j], bfr[2 + nf], acc[j][2 + nf]);
    __builtin_amdgcn_s_setprio(0);
    if (kt < NT - 2)       asm volatile("s_waitcnt vmcnt(4)" ::: "memory");
    else if (kt == NT - 2) asm volatile("s_waitcnt vmcnt(0)" ::: "memory");
    BAR();
    bql += 1; if (bql >= 3) bql -= 3;
  }

  // ---- epilogue: C write ----
#pragma unroll
  for (int mf = 0; mf < 4; ++mf) {
    int rowb = (int)m0 + wr * 64 + mf * 16 + lq * 4;
#pragma unroll
    for (int nf = 0; nf < 4; ++nf) {
      int col = n0 + wc * 64 + nf * 16 + l16;
#pragma unroll
      for (int r = 0; r < 4; ++r) {
        float v = acc[mf][nf][r];
        int mrow = rowb + r;
        if (MODE == 0) {
          int grp = col >> 11, cw = col & 2047;
          int b = mrow >> 11, s = mrow & 2047, n = cw >> 7, h = cw & 127;
          ((bf16*)Cout)[(size_t)grp * 8388608 +
                        (((size_t)(b * 16 + n) * 2048 + s) << 7) + h] = (bf16)v;
        } else {
          ((float*)Cout)[((size_t)mrow << 11) + col] = v;
        }
      }
    }
  }
}

// ------------- Flash attention (causal): Q,K [B,N,S,H], Vt [B,N,H,S] -> AO [B,S,N,H] -------------
// R2-verified structure (108us): single-buffer staging, padded Ps, __syncthreads,
// 3 blocks/CU. Added: T13 defer-max (skip O-rescale when max growth <= 8).
__global__ __launch_bounds__(512, 4) void k_attn(const bf16* __restrict__ Q,
                                                 const bf16* __restrict__ Kg,
                                                 const bf16* __restrict__ Vt,
                                                 bf16* __restrict__ AO) {
  __shared__ __align__(16) bf16 Ks[64 * 128];   // [s'][h], chunk-swizzled
  __shared__ __align__(16) bf16 Vs[128 * 64];   // [h][s'], chunk-swizzled
  __shared__ __align__(16) bf16 Ps[8][16][72];  // per-wave P, padded (+72: 2-way free)
  int bid = blockIdx.x;
  int half = bid >> 8;
  int bn = (half << 4) | ((bid >> 4) & 15);
  int qt = (bid & 15) ^ (half ? 15 : 0);
  int q0 = qt * 128;
  int t = threadIdx.x, wid = t >> 6, lane = t & 63;
  int l16 = lane & 15, lq = lane >> 4;
  size_t bnSH = (size_t)bn * kS * kH;

  int qrow_a = q0 + wid * 16 + l16;
  bf16x8 qf[4];
#pragma unroll
  for (int ks = 0; ks < 4; ++ks)
    qf[ks] = *(const bf16x8*)(Q + bnSH + (size_t)qrow_a * kH + ks * 32 + lq * 8);

  f32x4 oacc[8] = {};
  float mrun[4], lrun[4];
#pragma unroll
  for (int r = 0; r < 4; ++r) { mrun[r] = -1e30f; lrun[r] = 0.f; }

  int ntiles = (q0 + 128) >> 6;
  for (int kt = 0; kt < ntiles; ++kt) {
    int kv0 = kt * 64;
#pragma unroll
    for (int i = 0; i < 2; ++i) {
      int idx = i * 512 + t;
      {
        int row = idx >> 4, ch = idx & 15;
        int gch = ch ^ (row & 7);
        gload16(Kg + bnSH + (size_t)(kv0 + row) * kH + gch * 8,
                (char*)Ks + i * 8192 + wid * 1024);
      }
      {
        int row = idx >> 3, ch = idx & 7;
        int gch = ch ^ (row & 7);
        gload16(Vt + bnSH + (size_t)row * kS + kv0 + gch * 8,
                (char*)Vs + i * 8192 + wid * 1024);
      }
    }
    __syncthreads();

    f32x4 sacc[4] = {};
#pragma unroll
    for (int ks = 0; ks < 4; ++ks) {
#pragma unroll
      for (int ni = 0; ni < 4; ++ni) {
        int sp = ni * 16 + l16;
        int hb = (ks * 32 + lq * 8) * 2;
        bf16x8 kb = *(const bf16x8*)((const char*)Ks + sp * 256 + (hb ^ ((sp & 7) << 4)));
        sacc[ni] = MFMA_BF16(qf[ks], kb, sacc[ni]);
      }
    }

    bool need_mask = (kv0 + 63) > (q0 + wid * 16);
#pragma unroll
    for (int ni = 0; ni < 4; ++ni) {
      f32x4 v = sacc[ni] * kScale;
      if (need_mask) {
#pragma unroll
        for (int r = 0; r < 4; ++r) {
          int qrow = q0 + wid * 16 + lq * 4 + r;
          int col = kv0 + ni * 16 + l16;
          if (col > qrow) v[r] = -1e30f;
        }
      }
      sacc[ni] = v;
    }

    // ---- row maxima (wave-parallel) ----
    float pmv[4];
#pragma unroll
    for (int r = 0; r < 4; ++r) {
      float pm = fmaxf(fmaxf(sacc[0][r], sacc[1][r]),
                       fmaxf(sacc[2][r], sacc[3][r]));
      pm = fmaxf(pm, __shfl_xor(pm, 1));
      pm = fmaxf(pm, __shfl_xor(pm, 2));
      pm = fmaxf(pm, __shfl_xor(pm, 4));
      pm = fmaxf(pm, __shfl_xor(pm, 8));
      pmv[r] = pm;
    }
    // ---- T13 defer-max: rescale only when some row grew past mrun+8 ----
    bool growl = (pmv[0] > mrun[0] + 8.f) | (pmv[1] > mrun[1] + 8.f) |
                 (pmv[2] > mrun[2] + 8.f) | (pmv[3] > mrun[3] + 8.f);
    if (__any(growl)) {
#pragma unroll
      for (int r = 0; r < 4; ++r) {
        float mnew = fmaxf(mrun[r], pmv[r]);
        float alpha = exp2f((mrun[r] - mnew) * kLog2e);
        mrun[r] = mnew;
        lrun[r] *= alpha;
#pragma unroll
        for (int nj = 0; nj < 8; ++nj) oacc[nj][r] *= alpha;
      }
    }
#pragma unroll
    for (int r = 0; r < 4; ++r) {
      float rs = 0.f;
#pragma unroll
      for (int ni = 0; ni < 4; ++ni) {
        float p = exp2f((sacc[ni][r] - mrun[r]) * kLog2e);
        sacc[ni][r] = p;
        rs += p;
      }
      rs += __shfl_xor(rs, 1);
      rs += __shfl_xor(rs, 2);
      rs += __shfl_xor(rs, 4);
      rs += __shfl_xor(rs, 8);
      lrun[r] += rs;
    }

#pragma unroll
    for (int ni = 0; ni < 4; ++ni)
#pragma unroll
      for (int r = 0; r < 4; ++r)
        Ps[wid][lq * 4 + r][ni * 16 + l16] = (bf16)sacc[ni][r];

#pragma unroll
    for (int ks = 0; ks < 2; ++ks) {
      bf16x8 pa = *(const bf16x8*)&Ps[wid][l16][ks * 32 + lq * 8];
#pragma unroll
      for (int nj = 0; nj < 8; ++nj) {
        int h = nj * 16 + l16;
        int sb = (ks * 64 + lq * 16) ^ ((h & 7) << 4);
        bf16x8 vb = *(const bf16x8*)((const char*)Vs + h * 128 + sb);
        oacc[nj] = MFMA_BF16(pa, vb, oacc[nj]);
      }
    }
    __syncthreads();
  }

  int b = bn >> 4, n = bn & 15;
#pragma unroll
  for (int r = 0; r < 4; ++r) {
    float inv = 1.0f / lrun[r];
    int qrow = q0 + wid * 16 + lq * 4 + r;
#pragma unroll
    for (int nj = 0; nj < 8; ++nj) {
      float v = oacc[nj][r] * inv;
      AO[(((size_t)b * kS + qrow) * kN + n) * kH + nj * 16 + l16] = (bf16)v;
    }
  }
}

extern "C" void kernel_launch(void* const* d_in, const int* in_sizes, int n_in,
                              void* d_out, int out_size, void* d_ws, size_t ws_size,
                              hipStream_t stream) {
  (void)in_sizes; (void)n_in; (void)out_size; (void)ws_size;
  const float* x_q  = (const float*)d_in[0];
  const float* x_kv = (const float*)d_in[1];
  const float* WQ   = (const float*)d_in[2];
  const float* WK   = (const float*)d_in[3];
  const float* WV   = (const float*)d_in[4];
  const float* WO   = (const float*)d_in[5];
  float* out = (float*)d_out;
  char* w = (char*)d_ws;
  const size_t MB = 1ull << 20;
  bf16* xq  = (bf16*)(w + 0 * MB);    // 16MB; reused: trig tables, then AO
  bf16* xkv = (bf16*)(w + 16 * MB);   // 16MB; reused as Vt
  bf16* WqT = (bf16*)(w + 32 * MB);   // WqT/WkT/WvT contiguous = fused [6144][2048]
  bf16* WkT = (bf16*)(w + 40 * MB);
  bf16* WvT = (bf16*)(w + 48 * MB);
  bf16* WoT = (bf16*)(w + 56 * MB);
  bf16* Qb  = (bf16*)(w + 64 * MB);   // [B,N,S,H]; Kb=+16MB, Vb=+32MB (grp indexed)
  bf16* Kb  = (bf16*)(w + 80 * MB);
  bf16* Vb  = (bf16*)(w + 96 * MB);
  float* ctab = (float*)(w + 0 * MB); // lives in dead xq region (after QKV GEMM)
  float* stab = (float*)(w + 1 * MB);
  bf16* AO  = xq;                     // [B,S,N,H] — written by attn (tables dead by then)
  bf16* Vtb = xkv;                    // [B,N,H,S]

  k_cvt2<<<16384, 256, 0, stream>>>(x_q, x_kv, xq, xkv);
  k_tconv4<<<4096, 256, 0, stream>>>(WQ, WK, WV, WO, WqT, WkT, WvT, WoT);
  k_gemm8<0><<<768, 512, 0, stream>>>(xq, xkv, WqT, Qb);   // fused QKV
  k_trig<<<512, 256, 0, stream>>>(ctab, stab);             // xq dead -> tables
  k_rope<<<2048, 256, 0, stream>>>(Qb, Kb, ctab, stab);
  k_vtrans<<<2048, 256, 0, stream>>>(Vb, Vtb);
  k_attn<<<512, 512, 0, stream>>>(Qb, Kb, Vtb, AO);        // AO overwrites tables (dead)
  k_gemm8<1><<<256, 512, 0, stream>>>(AO, AO, WoT, out);   // output proj
}